// Round 9
// baseline (193.529 us; speedup 1.0000x reference)
//
#include <hip/hip_runtime.h>
#include <hip/hip_bf16.h>
#include <hip/hip_fp8.h>

typedef __attribute__((ext_vector_type(4))) int i32x4;
typedef __attribute__((ext_vector_type(8))) int i32x8;
typedef __attribute__((ext_vector_type(16))) float f32x16;

#define MARGIN 0.3f
#define BIGF 3.0e38f

__device__ __forceinline__ void gl2lds16(const void* g, void* l) {
    __builtin_amdgcn_global_load_lds(
        (const __attribute__((address_space(1))) void*)g,
        (__attribute__((address_space(3))) void*)l,
        16, 0, 0);
}

// Wave-per-row convert: fp32 -> fp8 e4m3 (OCP) cast, fp32 row norm of the
// fp8-ROUNDED values (consistent with MFMA dots -> exact diagonal), init
// ap/an/cnt. 4 rows per 256-thread block. (R7/R8-verified.)
__global__ __launch_bounds__(256) void convert_norm_kernel(
    const float* __restrict__ X, unsigned char* __restrict__ Xq,
    float* __restrict__ nrm, unsigned* __restrict__ ap,
    unsigned* __restrict__ an, unsigned* __restrict__ cnt, int K) {
    const int wave = threadIdx.x >> 6, lane = threadIdx.x & 63;
    const int row = blockIdx.x * 4 + wave;
    const float* xr = X + (size_t)row * K;
    unsigned char* xqr = Xq + (size_t)row * K;
    float s = 0.0f;
    for (int c = lane * 8; c < K; c += 64 * 8) {
        float4 v0 = *(const float4*)(xr + c);
        float4 v1 = *(const float4*)(xr + c + 4);
        float f[8] = {v0.x, v0.y, v0.z, v0.w, v1.x, v1.y, v1.z, v1.w};
        union { unsigned char b[8]; uint2 u; } p;
#pragma unroll
        for (int i = 0; i < 8; i++) {
            __hip_fp8_e4m3 q(f[i]);       // OCP e4m3, RNE+saturate
            p.b[i] = q.__x;
            float d = (float)q;           // decoded value
            s += d * d;
        }
        *(uint2*)(xqr + c) = p.u;
    }
    for (int off = 32; off > 0; off >>= 1) s += __shfl_xor(s, off, 64);
    if (lane == 0) {
        nrm[row] = s;
        ap[row] = 0u;           // dist_ap >= 0 always (self is a positive)
        an[row] = 0x7F800000u;  // +inf
        if (row == 0) *cnt = 0u;
    }
}

// SINGLE-WAVE blocks (64 threads), wave-private 64x64 fp8 tile, BK=128.
// LDS = exactly 16 KB -> 10 blocks resident per CU (the R8 limiter was
// TLP: ~4 lockstep blocks/CU left vmcnt(0) L2 latency exposed; here 10
// independent single-wave pipelines hide it). 2080 upper-triangle 64x64
// tiles at N=4096. No cross-wave coupling, no s_barrier: per iter the
// wave stages its own A/B (16 gl2lds, R7-verified lane math + XOR
// swizzle), waits vmcnt(0) on its own loads, computes 2 k64-steps
// (4 mfma_scale_32x32x64 per step-pair), then lgkmcnt(0) before
// restaging the single buffer. Epilogue fully wave-local (R6-verified
// style, R7-verified 32x32 C/D map); monotone uint atomics; last block
// (shfl-broadcast done-count, no LDS) computes the loss.
__global__ __launch_bounds__(64) void gemm_reduce_kernel(
    const unsigned char* __restrict__ Xq, const float* __restrict__ nrm,
    const int* __restrict__ Y, unsigned* __restrict__ ap,
    unsigned* __restrict__ an, unsigned* __restrict__ cnt,
    float* __restrict__ out, int N, int K) {
    __shared__ __align__(16) unsigned char sA[64 * 128];  // 8 KB
    __shared__ __align__(16) unsigned char sB[64 * 128];  // 8 KB

    const int lane = threadIdx.x;  // single wave
    const int m = lane & 31;       // row/col within 32x32 subtile
    const int h = lane >> 5;       // k-half (inputs) / row-group (outputs)

    // Decode 64x64 upper-triangle tile index.
    const int NB = N >> 6;
    int ib = 0, rem = blockIdx.x;
    while (rem >= NB - ib) { rem -= NB - ib; ib++; }
    const int rowB = ib * 64;
    const int colB = (ib + rem) * 64;

    f32x16 acc[2][2];
#pragma unroll
    for (int si = 0; si < 2; si++)
#pragma unroll
        for (int sj = 0; sj < 2; sj++)
#pragma unroll
            for (int rr = 0; rr < 16; rr++) acc[si][sj][rr] = 0.0f;

    // Staging: lane l -> LDS row l>>3 (8-row group), physical 16B chunk
    // l&7; fetches LOGICAL chunk (l&7)^(l>>3) so phys = logical ^ (row&7).
    const int rsub = lane >> 3;
    const int jchunk = (lane & 7) ^ rsub;
    const unsigned char* gA = Xq + (size_t)(rowB + rsub) * K + jchunk * 16;
    const unsigned char* gB = Xq + (size_t)(colB + rsub) * K + jchunk * 16;
    const size_t g8 = (size_t)8 * K;  // 8 rows, bytes

    const int e = m & 7;     // unswizzle key (row&7 = m&7; row offsets are mult of 32)
    const int nit = K >> 7;  // BK=128

    for (int it = 0; it < nit; it++) {
        const size_t go = (size_t)it * 128;  // 128 k-elems * 1 B
#pragma unroll
        for (int gi = 0; gi < 8; gi++)
            gl2lds16(gA + go + gi * g8, sA + gi * 1024);
#pragma unroll
        for (int gi = 0; gi < 8; gi++)
            gl2lds16(gB + go + gi * g8, sB + gi * 1024);
        // Wait for OUR 16 loads only — no barrier, no other waves involved.
        asm volatile("s_waitcnt vmcnt(0)" ::: "memory");

#pragma unroll
        for (int s = 0; s < 2; s++) {      // two k64 steps per BK=128
            const int c0 = s * 4 + h * 2;  // logical 16B chunk of this k-half
            i32x8 af[2], bf[2];
#pragma unroll
            for (int si = 0; si < 2; si++) {
                const unsigned char* base = sA + (si * 32 + m) * 128;
                i32x4 lo = *(const i32x4*)(base + ((c0 ^ e) * 16));
                i32x4 hi = *(const i32x4*)(base + (((c0 + 1) ^ e) * 16));
                af[si] = __builtin_shufflevector(lo, hi, 0, 1, 2, 3, 4, 5, 6, 7);
            }
#pragma unroll
            for (int sj = 0; sj < 2; sj++) {
                const unsigned char* base = sB + (sj * 32 + m) * 128;
                i32x4 lo = *(const i32x4*)(base + ((c0 ^ e) * 16));
                i32x4 hi = *(const i32x4*)(base + (((c0 + 1) ^ e) * 16));
                bf[sj] = __builtin_shufflevector(lo, hi, 0, 1, 2, 3, 4, 5, 6, 7);
            }
#pragma unroll
            for (int si = 0; si < 2; si++)
#pragma unroll
                for (int sj = 0; sj < 2; sj++)
                    acc[si][sj] = __builtin_amdgcn_mfma_scale_f32_32x32x64_f8f6f4(
                        af[si], bf[sj], acc[si][sj], 0 /*A fmt fp8*/,
                        0 /*B fmt fp8*/, 0, 127 /*scale A = 2^0*/,
                        0, 127 /*scale B = 2^0*/);
        }
        // Reads must complete before next iter's gl2lds overwrites the buffer.
        asm volatile("s_waitcnt lgkmcnt(0)" ::: "memory");
    }

    // Wave-local epilogue. C/D: col = sj*32 + m, row = si*32 + (reg&3) +
    // 8*(reg>>2) + 4*h. Per-lane labels/norms loaded from global (L2-hot).
    int yc[2]; float ncv[2];
#pragma unroll
    for (int sj = 0; sj < 2; sj++) {
        yc[sj] = Y[colB + sj * 32 + m];
        ncv[sj] = nrm[colB + sj * 32 + m];
    }

    float cmx[2], cmn[2];
    cmx[0] = cmx[1] = -1.0f;
    cmn[0] = cmn[1] = BIGF;

#pragma unroll
    for (int si = 0; si < 2; si++)
#pragma unroll
        for (int reg = 0; reg < 16; reg++) {
            const int r64 = si * 32 + (reg & 3) + 8 * (reg >> 2) + 4 * h;
            const int yr = Y[rowB + r64];      // wave-uniform per h -> broadcast
            const float nr = nrm[rowB + r64];
            float dp = -1.0f, dn = BIGF;
#pragma unroll
            for (int sj = 0; sj < 2; sj++) {
                float d2 = nr + ncv[sj] - 2.0f * acc[si][sj][reg];
                float d = sqrtf(fmaxf(d2, 0.0f));
                bool same = (yr == yc[sj]);
                float p = same ? d : -1.0f;
                float n = same ? BIGF : d;
                dp = fmaxf(dp, p);
                dn = fminf(dn, n);
                cmx[sj] = fmaxf(cmx[sj], p);
                cmn[sj] = fminf(cmn[sj], n);
            }
            // Row-side: reduce over the 32 col-lanes (offsets < 32 keep h).
            for (int off = 1; off < 32; off <<= 1) {
                dp = fmaxf(dp, __shfl_xor(dp, off, 64));
                dn = fminf(dn, __shfl_xor(dn, off, 64));
            }
            if (m == 0) {  // lanes 0 (h=0) and 32 (h=1): disjoint r64 sets
                atomicMax(&ap[rowB + r64], __float_as_uint(fmaxf(dp, 0.0f)));
                atomicMin(&an[rowB + r64], __float_as_uint(dn));
            }
        }

    // Col-side: merge the two h row-groups; h==0 lanes own cols sj*32+m.
#pragma unroll
    for (int sj = 0; sj < 2; sj++) {
        float mx = fmaxf(cmx[sj], __shfl_xor(cmx[sj], 32, 64));
        float mn = fminf(cmn[sj], __shfl_xor(cmn[sj], 32, 64));
        if (h == 0) {
            atomicMax(&ap[colB + sj * 32 + m], __float_as_uint(fmaxf(mx, 0.0f)));
            atomicMin(&an[colB + sj * 32 + m], __float_as_uint(mn));
        }
    }

    // Last block computes the loss. Single wave: broadcast the done-count
    // via shfl (no LDS -> keeps LDS_Block_Size at exactly 16 KB).
    unsigned mydone = 0;
    if (lane == 0) {
        __threadfence();  // release our ap/an updates
        mydone = atomicAdd(cnt, 1u);
    }
    const unsigned done = __shfl(mydone, 0, 64);
    if (done == gridDim.x - 1) {
        __threadfence();  // acquire all blocks' updates
        float s = 0.0f;
        for (int i = lane; i < N; i += 64) {
            unsigned ua = __hip_atomic_load(&ap[i], __ATOMIC_RELAXED,
                                            __HIP_MEMORY_SCOPE_AGENT);
            unsigned ub = __hip_atomic_load(&an[i], __ATOMIC_RELAXED,
                                            __HIP_MEMORY_SCOPE_AGENT);
            s += fmaxf(__uint_as_float(ua) - __uint_as_float(ub) + MARGIN, 0.0f);
        }
        for (int off = 32; off > 0; off >>= 1) s += __shfl_xor(s, off, 64);
        if (lane == 0) out[0] = s / (float)N;
    }
}

extern "C" void kernel_launch(void* const* d_in, const int* in_sizes, int n_in,
                              void* d_out, int out_size, void* d_ws, size_t ws_size,
                              hipStream_t stream) {
    const float* X = (const float*)d_in[0];
    const int* Y = (const int*)d_in[1];
    float* out = (float*)d_out;
    const int N = in_sizes[1];          // 4096
    const int K = in_sizes[0] / N;      // 2048

    char* ws = (char*)d_ws;
    unsigned char* Xq = (unsigned char*)ws;                         // N*K bytes
    float* nrm = (float*)(ws + (size_t)N * K);
    unsigned* ap = (unsigned*)((char*)nrm + (size_t)N * 4);
    unsigned* an = (unsigned*)((char*)ap + (size_t)N * 4);
    unsigned* cnt = (unsigned*)((char*)an + (size_t)N * 4);

    convert_norm_kernel<<<N / 4, 256, 0, stream>>>(X, Xq, nrm, ap, an, cnt, K);
    const int NB = N / 64;
    const int ntiles = NB * (NB + 1) / 2;  // 2080 64x64 upper-triangle tiles
    gemm_reduce_kernel<<<ntiles, 64, 0, stream>>>(Xq, nrm, Y, ap, an, cnt,
                                                  out, N, K);
}